// Round 1
// baseline (8805.730 us; speedup 1.0000x reference)
//
#include <hip/hip_runtime.h>
#include <hip/hip_bf16.h>

// ---------------------------------------------------------------------------
// UnifiedModelRNN: B=256,S=512,I=64,H=256. Sequential scan, batch-parallel.
// 16 workgroups x 512 threads; wg g owns batch rows [16g,16g+16) for all t.
// Weights bf16 (prepped into d_ws); gates GEMM via mfma_f32_16x16x32_bf16,
// weights streamed global->VGPR (L2-resident); c-state in registers.
// ---------------------------------------------------------------------------

typedef float f32x4 __attribute__((ext_vector_type(4)));
typedef short s16x8 __attribute__((ext_vector_type(8)));

#define S_LEN 512
#define I_DIM 64
#define H_DIM 256
#define K_DIM 320
#define BT    16
#define NT    512

// ws element offsets (unsigned short = bf16 storage)
#define WS_WC    0        // Wc: 1024 x 320 row-major, [w_ih | w_hh]
#define WS_PW1   327680   // pit_w1: 64 x 256
#define WS_TW1   344064   // time_w1[:, :256]: 64 x 256
#define WS_ARW1X 360448   // ar_w1[:, 2:66]: 64 x 64
#define WS_ARW2  364544   // ar_w2: 64 x 64
#define WS_TOTAL 368640

#define OUT_PIT  0
#define OUT_TIME 131072
#define OUT_AR   262144

#define ALD 328   // [x_t|h] LDS row stride (bf16 elems); 656B = 41*16 -> aligned, bank-spread
#define XLD 72    // small 16x64 tiles row stride; 144B

__device__ __forceinline__ float sigf(float x) {
  return 1.0f / (1.0f + __expf(-x));
}
__device__ __forceinline__ float tanh_fast(float x) {
  float c = fminf(fmaxf(x, -15.0f), 15.0f);
  float e = __expf(2.0f * c);
  return (e - 1.0f) / (e + 1.0f);
}
__device__ __forceinline__ unsigned short f2bf(float f) {
  __hip_bfloat16 h = __float2bfloat16(f);
  return *reinterpret_cast<unsigned short*>(&h);
}

__global__ void prep_kernel(const float* __restrict__ w_ih,
                            const float* __restrict__ w_hh,
                            const float* __restrict__ pit_w1,
                            const float* __restrict__ time_w1,
                            const float* __restrict__ ar_w1,
                            const float* __restrict__ ar_w2,
                            unsigned short* __restrict__ ws) {
  int idx = blockIdx.x * 256 + threadIdx.x;
  if (idx >= WS_TOTAL) return;
  float v;
  if (idx < WS_PW1) {
    int r = idx / K_DIM;
    int k = idx - r * K_DIM;
    v = (k < I_DIM) ? w_ih[r * I_DIM + k] : w_hh[r * H_DIM + (k - I_DIM)];
  } else if (idx < WS_TW1) {
    v = pit_w1[idx - WS_PW1];
  } else if (idx < WS_ARW1X) {
    int e = idx - WS_TW1;
    int j = e >> 8, k = e & 255;
    v = time_w1[j * 257 + k];
  } else if (idx < WS_ARW2) {
    int e = idx - WS_ARW1X;
    int j = e >> 6, k = e & 63;
    v = ar_w1[j * 66 + 2 + k];
  } else {
    v = ar_w2[idx - WS_ARW2];
  }
  ws[idx] = f2bf(v);
}

__global__ __launch_bounds__(NT, 2) void rnn_kernel(
    const float* __restrict__ x,
    const float* __restrict__ b_ih, const float* __restrict__ b_hh,
    const float* __restrict__ pit_b1, const float* __restrict__ pit_w2,
    const float* __restrict__ pit_b2,
    const float* __restrict__ time_w1, const float* __restrict__ time_b1,
    const float* __restrict__ time_w2, const float* __restrict__ time_b2,
    const float* __restrict__ ar_w1, const float* __restrict__ ar_b1,
    const float* __restrict__ ar_b2,
    const unsigned short* __restrict__ ws,
    float* __restrict__ out)
{
  __shared__ __align__(16) unsigned short A_lds[16][ALD];    // [x_t(64) | h(256)] bf16
  __shared__ __align__(16) unsigned short xo_lds[16][XLD];   // x_orig[t] bf16
  __shared__ __align__(16) unsigned short ar1_lds[16][XLD];  // relu(ar1) bf16
  __shared__ float pitp[4][16];
  __shared__ float timep[4][16];

  const int tid  = threadIdx.x;
  const int wave = tid >> 6;
  const int lane = tid & 63;
  const int lrow = lane & 15;   // MFMA: A-row / B-col / D-col
  const int lgrp = lane >> 4;   // MFMA: k-group / D-row-group
  const int b0   = blockIdx.x * BT;

  // ---- init: zero h-section (+pad), stage x[:,0,:], write ar_out[:,0,:] ----
  for (int i = tid; i < 16 * (ALD - 64); i += NT) {
    int r = i / (ALD - 64), c = 64 + i % (ALD - 64);
    A_lds[r][c] = 0;
  }
  {
    int row = tid >> 5;
    int c2  = (tid & 31) * 2;
    const float2 xv = *reinterpret_cast<const float2*>(
        &x[(size_t)(b0 + row) * S_LEN * I_DIM + c2]);
    A_lds[row][c2]     = f2bf(xv.x);
    A_lds[row][c2 + 1] = f2bf(xv.y);
    out[OUT_AR + (size_t)(b0 + row) * S_LEN * I_DIM + c2]     = xv.x;
    out[OUT_AR + (size_t)(b0 + row) * S_LEN * I_DIM + c2 + 1] = xv.y;
  }

  // ---- per-lane stationary constants ----
  float bias_qm[4][2];
  int   woff[4][2];
#pragma unroll
  for (int q = 0; q < 4; ++q) {
#pragma unroll
    for (int m = 0; m < 2; ++m) {
      int g = q * 256 + wave * 32 + m * 16 + lrow;
      bias_qm[q][m] = b_ih[g] + b_hh[g];
      woff[q][m]    = g * K_DIM + 8 * lgrp;
    }
  }
  const int hc = (wave < 4 ? wave : wave - 4) * 16 + lrow;  // head col 0..63
  float hb1 = 0, hw2 = 0, hwlast = 0, harp = 0, hart = 0, harb1 = 0, harb2 = 0;
  if (wave < 4) {
    hb1   = pit_b1[hc];
    hw2   = pit_w2[hc];
    harb1 = ar_b1[hc];
    harp  = ar_w1[hc * 66 + 0];
    hart  = ar_w1[hc * 66 + 1];
  } else {
    hb1    = time_b1[hc];
    hw2    = time_w2[hc];
    hwlast = time_w1[hc * 257 + 256];
    harb2  = ar_b2[hc];
  }
  const float pb2 = pit_b2[0], tb2 = time_b2[0];

  float cst[2][4];
#pragma unroll
  for (int m = 0; m < 2; ++m)
#pragma unroll
    for (int r = 0; r < 4; ++r) cst[m][r] = 0.0f;

  __syncthreads();

  // =========================== time loop ===========================
  for (int t = 0; t < S_LEN; ++t) {
    // stage x_orig[t] (read in P2; covered by sync_0/sync_a)
    {
      int row = tid >> 5;
      int c2  = (tid & 31) * 2;
      const float2 xv = *reinterpret_cast<const float2*>(
          &x[(size_t)(b0 + row) * S_LEN * I_DIM + (size_t)t * I_DIM + c2]);
      xo_lds[row][c2]     = f2bf(xv.x);
      xo_lds[row][c2 + 1] = f2bf(xv.y);
    }

    // ---- gates: 16x1024 = (16x320)@(320x1024), wave w owns hidden [32w,32w+32) ----
    f32x4 acc[4][2];
#pragma unroll
    for (int q = 0; q < 4; ++q)
#pragma unroll
      for (int m = 0; m < 2; ++m) {
        float bb = bias_qm[q][m];
        f32x4 tv; tv[0] = bb; tv[1] = bb; tv[2] = bb; tv[3] = bb;
        acc[q][m] = tv;
      }
#pragma unroll
    for (int kt = 0; kt < 10; ++kt) {
      s16x8 a = *reinterpret_cast<const s16x8*>(&A_lds[lrow][kt * 32 + 8 * lgrp]);
#pragma unroll
      for (int q = 0; q < 4; ++q)
#pragma unroll
        for (int m = 0; m < 2; ++m) {
          s16x8 b = *reinterpret_cast<const s16x8*>(&ws[WS_WC + woff[q][m] + kt * 32]);
          acc[q][m] = __builtin_amdgcn_mfma_f32_16x16x32_bf16(a, b, acc[q][m], 0, 0, 0);
        }
    }
    __syncthreads();  // sync_0: all gate reads of A_lds done before h overwrite

    // ---- LSTM update (per-lane; c in regs), write h bf16 into A_lds ----
#pragma unroll
    for (int m = 0; m < 2; ++m)
#pragma unroll
      for (int r = 0; r < 4; ++r) {
        float ig = sigf(acc[0][m][r]);
        float fg = sigf(acc[1][m][r]);
        float gg = tanh_fast(acc[2][m][r]);
        float og = sigf(acc[3][m][r]);
        float c  = fg * cst[m][r] + ig * gg;
        cst[m][r] = c;
        float h = og * tanh_fast(c);
        A_lds[lgrp * 4 + r][64 + wave * 32 + m * 16 + lrow] = f2bf(h);
      }
    __syncthreads();  // sync_a: h ready

    // ---- P1: waves 0-3 pit1, waves 4-7 time1-main (both K=256 over h) ----
    f32x4 hacc;
    hacc[0] = hb1; hacc[1] = hb1; hacc[2] = hb1; hacc[3] = hb1;
    {
      const unsigned short* wsel = ws + (wave < 4 ? WS_PW1 : WS_TW1) + hc * 256 + 8 * lgrp;
#pragma unroll
      for (int kt = 0; kt < 8; ++kt) {
        s16x8 a = *reinterpret_cast<const s16x8*>(&A_lds[lrow][64 + kt * 32 + 8 * lgrp]);
        s16x8 b = *reinterpret_cast<const s16x8*>(&wsel[kt * 32]);
        hacc = __builtin_amdgcn_mfma_f32_16x16x32_bf16(a, b, hacc, 0, 0, 0);
      }
    }
    if (wave < 4) {
      float v[4];
#pragma unroll
      for (int r = 0; r < 4; ++r) v[r] = fmaxf(hacc[r], 0.0f) * hw2;
#pragma unroll
      for (int off = 1; off < 16; off <<= 1)
#pragma unroll
        for (int r = 0; r < 4; ++r) v[r] += __shfl_xor(v[r], off);
      if (lrow == 0) {
#pragma unroll
        for (int r = 0; r < 4; ++r) pitp[wave][lgrp * 4 + r] = v[r];
      }
    }
    __syncthreads();  // sync_c: pit partials ready

    // ---- P2: waves 0-3 ar1-x MFMA (K=64 over x_orig); waves 4-7 time finish ----
    f32x4 aracc;
    if (wave < 4) {
      aracc[0] = harb1; aracc[1] = harb1; aracc[2] = harb1; aracc[3] = harb1;
#pragma unroll
      for (int kt = 0; kt < 2; ++kt) {
        s16x8 a = *reinterpret_cast<const s16x8*>(&xo_lds[lrow][kt * 32 + 8 * lgrp]);
        s16x8 b = *reinterpret_cast<const s16x8*>(&ws[WS_ARW1X + hc * 64 + kt * 32 + 8 * lgrp]);
        aracc = __builtin_amdgcn_mfma_f32_16x16x32_bf16(a, b, aracc, 0, 0, 0);
      }
      if (wave == 0 && lane < 16) {
        float pv = pitp[0][lane] + pitp[1][lane] + pitp[2][lane] + pitp[3][lane] + pb2;
        out[OUT_PIT + (size_t)(b0 + lane) * S_LEN + t] = pv;
      }
    } else {
      float v[4];
#pragma unroll
      for (int r = 0; r < 4; ++r) {
        int row = lgrp * 4 + r;
        float pv = pitp[0][row] + pitp[1][row] + pitp[2][row] + pitp[3][row] + pb2;
        v[r] = fmaxf(hacc[r] + pv * hwlast, 0.0f) * hw2;
      }
#pragma unroll
      for (int off = 1; off < 16; off <<= 1)
#pragma unroll
        for (int r = 0; r < 4; ++r) v[r] += __shfl_xor(v[r], off);
      if (lrow == 0) {
#pragma unroll
        for (int r = 0; r < 4; ++r) timep[wave - 4][lgrp * 4 + r] = v[r];
      }
    }
    __syncthreads();  // sync_d: time partials ready

    // ---- P3: waves 0-3 finish ar1 (+pit,+time), relu -> ar1_lds; wave4 writes time ----
    if (wave < 4) {
#pragma unroll
      for (int r = 0; r < 4; ++r) {
        int row = lgrp * 4 + r;
        float pv = pitp[0][row] + pitp[1][row] + pitp[2][row] + pitp[3][row] + pb2;
        float tv = timep[0][row] + timep[1][row] + timep[2][row] + timep[3][row] + tb2;
        float a1 = aracc[r] + pv * harp + tv * hart;
        ar1_lds[row][hc] = f2bf(fmaxf(a1, 0.0f));
      }
    } else if (wave == 4 && lane < 16) {
      float tv = timep[0][lane] + timep[1][lane] + timep[2][lane] + timep[3][lane] + tb2;
      out[OUT_TIME + (size_t)(b0 + lane) * S_LEN + t] = tv;
    }
    __syncthreads();  // sync_e: ar1 ready

    // ---- P4: waves 4-7 ar2 -> nxt; write ar_out[t+1] + next x_t into A_lds ----
    if (wave >= 4) {
      f32x4 nacc;
      nacc[0] = harb2; nacc[1] = harb2; nacc[2] = harb2; nacc[3] = harb2;
#pragma unroll
      for (int kt = 0; kt < 2; ++kt) {
        s16x8 a = *reinterpret_cast<const s16x8*>(&ar1_lds[lrow][kt * 32 + 8 * lgrp]);
        s16x8 b = *reinterpret_cast<const s16x8*>(&ws[WS_ARW2 + hc * 64 + kt * 32 + 8 * lgrp]);
        nacc = __builtin_amdgcn_mfma_f32_16x16x32_bf16(a, b, nacc, 0, 0, 0);
      }
#pragma unroll
      for (int r = 0; r < 4; ++r) {
        int row = lgrp * 4 + r;
        float nv = nacc[r];
        if (t < S_LEN - 1)
          out[OUT_AR + (size_t)(b0 + row) * S_LEN * I_DIM + (size_t)(t + 1) * I_DIM + hc] = nv;
        A_lds[row][hc] = f2bf(nv);
      }
    }
    __syncthreads();  // sync_f: next x_t staged
  }
}

extern "C" void kernel_launch(void* const* d_in, const int* in_sizes, int n_in,
                              void* d_out, int out_size, void* d_ws, size_t ws_size,
                              hipStream_t stream) {
  const float* x       = (const float*)d_in[0];
  const float* w_ih    = (const float*)d_in[1];
  const float* w_hh    = (const float*)d_in[2];
  const float* b_ih    = (const float*)d_in[3];
  const float* b_hh    = (const float*)d_in[4];
  const float* pit_w1  = (const float*)d_in[5];
  const float* pit_b1  = (const float*)d_in[6];
  const float* pit_w2  = (const float*)d_in[7];
  const float* pit_b2  = (const float*)d_in[8];
  const float* time_w1 = (const float*)d_in[9];
  const float* time_b1 = (const float*)d_in[10];
  const float* time_w2 = (const float*)d_in[11];
  const float* time_b2 = (const float*)d_in[12];
  const float* ar_w1   = (const float*)d_in[13];
  const float* ar_b1   = (const float*)d_in[14];
  const float* ar_w2   = (const float*)d_in[15];
  const float* ar_b2   = (const float*)d_in[16];
  unsigned short* ws   = (unsigned short*)d_ws;
  float* out           = (float*)d_out;

  prep_kernel<<<dim3((WS_TOTAL + 255) / 256), dim3(256), 0, stream>>>(
      w_ih, w_hh, pit_w1, time_w1, ar_w1, ar_w2, ws);
  rnn_kernel<<<dim3(16), dim3(NT), 0, stream>>>(
      x, b_ih, b_hh, pit_b1, pit_w2, pit_b2,
      time_w1, time_b1, time_w2, time_b2,
      ar_w1, ar_b1, ar_b2, ws, out);
}